// Round 18
// baseline (305.712 us; speedup 1.0000x reference)
//
// Round 18: interleave MLP-r and MLP-i. r15/r17 falsified occupancy as the
// lever (22->42% occ = -8%; bound-4 neutral) -> stalls are INTRA-WAVE serial
// chains (MFMA->silu(trans)->cvt->ds_write->ds_read->MFMA), and the two MLPs
// ran sequentially through one H buffer, blocking overlap. Now both MLPs
// share each nt iteration (6/8 MFMAs + 2 silu chains in flight = 2x ILP at
// every latency point). Separate Hr/Hi buffers: LDS 49152 (3 blocks/CU,
// proven non-binding). Spill signature = FETCH explosion (r12 lesson).
#include <hip/hip_runtime.h>

#define PI_F     3.14159265358979323846f
#define TWO_PI_F 6.28318530717958647692f

typedef __attribute__((ext_vector_type(8))) _Float16 half8;
typedef __attribute__((ext_vector_type(4))) float f32x4;

#define LO_SCALE   2048.0f
#define LO_INV     (1.0f / 2048.0f)

__device__ __forceinline__ float fast_rcp(float x) { return __builtin_amdgcn_rcpf(x); }
__device__ __forceinline__ float silu_f(float v) { return v * fast_rcp(1.0f + __expf(-v)); }
__device__ __forceinline__ float tanh_f(float z) {
    float ez = __expf(2.0f * z);
    return 1.0f - 2.0f * fast_rcp(ez + 1.0f);
}

// ---------------- prep: fragment-ordered fp16 hi / scaled-lo weight planes --
// Fragment layout validated r8-r17: per MLP (u16): L1 [0,2048) KT=1 NT=4;
// L2 [2048,6144) KT=2 NT=4; L3 [6144,7168) KT=2 NT=1. MLP i at +7168.
// hi plane [0,14336), scaled-lo plane [14336,28672).
// Frag elem ((kt*NT+nt)*64+lane)*8+j = W[kt*32+8*(lane>>4)+j][nt*16+(lane&15)].
#define WS_U16_TOTAL 28672
#define WS_BYTES_NEEDED (WS_U16_TOTAL * 2)
#define W_HI_U16 14336

__global__ __launch_bounds__(256) void qgnn_prep_kernel(
    const float* __restrict__ Wr1, const float* __restrict__ Wr2, const float* __restrict__ Wr3,
    const float* __restrict__ Wi1, const float* __restrict__ Wi2, const float* __restrict__ Wi3,
    unsigned short* __restrict__ wsu)
{
    int idx = blockIdx.x * 256 + threadIdx.x;
    if (idx >= 14336) return;
    int rel = idx;
    int half = (rel >= 7168);
    if (half) rel -= 7168;
    const float* W; int base, NT, Kr, Nr;
    if (rel < 2048)      { W = half ? Wi1 : Wr1; base = 0;    NT = 4; Kr = 14; Nr = 64; }
    else if (rel < 6144) { W = half ? Wi2 : Wr2; base = 2048; NT = 4; Kr = 64; Nr = 64; }
    else                 { W = half ? Wi3 : Wr3; base = 6144; NT = 1; Kr = 64; Nr = 4;  }
    int f = rel - base;
    int frag = f >> 9, rem = f & 511;
    int l = rem >> 3, j = rem & 7;
    int nt = frag % NT, kt = frag / NT;
    int k = kt * 32 + ((l >> 4) << 3) + j;
    int n = nt * 16 + (l & 15);
    float v = (k < Kr && n < Nr) ? W[k * Nr + n] : 0.0f;
    _Float16 hi = (_Float16)v;                                  // RNE
    _Float16 lo = (_Float16)((v - (float)hi) * LO_SCALE);       // scaled residual
    wsu[idx] = *reinterpret_cast<unsigned short*>(&hi);
    wsu[14336 + idx] = *reinterpret_cast<unsigned short*>(&lo);
}

__global__ __launch_bounds__(256) void qgnn_zero_kernel(float* __restrict__ p, int n) {
    const int i = blockIdx.x * blockDim.x + threadIdx.x;
    if (i < n) p[i] = 0.0f;
}

#define MFMA16(a, b, c) __builtin_amdgcn_mfma_f32_16x16x32_f16((a), (b), (c), 0, 0, 0)
#define NW 4   // waves per block

__global__ __launch_bounds__(256, 3) void qgnn_edge_mfma_kernel(
    const float* __restrict__ hr, const float* __restrict__ hi_,
    const int* __restrict__ ei,
    const float* __restrict__ npar, const float* __restrict__ epar,
    const float* __restrict__ Wa, const float* __restrict__ ba,
    const float* __restrict__ br1, const float* __restrict__ br2, const float* __restrict__ br3,
    const float* __restrict__ bi1, const float* __restrict__ bi2, const float* __restrict__ bi3,
    const unsigned short* __restrict__ wsu,
    float* __restrict__ aggout, int E, int stride)
{
    __shared__ __align__(16) _Float16 sW[W_HI_U16];            // 28672 B (hi plane)
    __shared__ __align__(16) _Float16 sH[NW][2 * 16 * 72];     // 4x4608 B (Hr | Hi)
    __shared__ __align__(16) float sH3[NW][16 * 8];            // 4x512 B
    // total 49152 B -> 3 blocks/CU

    // ---- stage hi-plane weights once (the only barrier in this kernel) ----
    {
        unsigned short* sWu = reinterpret_cast<unsigned short*>(sW);
        for (int o = threadIdx.x * 8; o < W_HI_U16; o += 256 * 8)
            *reinterpret_cast<uint4*>(sWu + o) = *reinterpret_cast<const uint4*>(wsu + o);
    }
    __syncthreads();

    const int tid = threadIdx.x, w = tid >> 6, lane = tid & 63;
    const int m16 = lane & 15, g = lane >> 4;
    _Float16* Hr = sH[w];
    _Float16* Hi = sH[w] + 16 * 72;
    float* H3 = sH3[w];

    // ---- per-lane constants: vector-typed, by-value use only (registers) ----
    f32x4 br1v, br2v, bi1v, bi2v;
    #pragma unroll
    for (int q = 0; q < 4; ++q) {
        br1v[q] = br1[q * 16 + m16];
        br2v[q] = br2[q * 16 + m16];
        bi1v[q] = bi1[q * 16 + m16];
        bi2v[q] = bi2[q * 16 + m16];
    }
    const float br3v = (m16 < 4) ? br3[m16] : 0.0f;
    const float bi3v = (m16 < 4) ? bi3[m16] : 0.0f;
    float wav[24], bav[3];
    #pragma unroll
    for (int q = 0; q < 24; ++q) wav[q] = Wa[q];
    #pragma unroll
    for (int q = 0; q < 3; ++q) bav[q] = ba[q];

    const _Float16*       whR = sW;                     // LDS hi, MLP r
    const _Float16*       whI = sW + 7168;              // LDS hi, MLP i
    const unsigned short* wlR = wsu + W_HI_U16;         // global scaled-lo, MLP r
    const unsigned short* wlI = wsu + W_HI_U16 + 7168;  // global scaled-lo, MLP i

    const int ntiles = (E + 15) >> 4;
    for (int tile = blockIdx.x * NW + w; tile < ntiles; tile += gridDim.x * NW) {
        const int em = tile * 16 + m16;
        const bool valid = (em < E);

        // ---- gather X straight into registers (no LDS, no barrier) ----
        float f0[8], f1[8];
        #pragma unroll
        for (int j = 0; j < 8; ++j) { f0[j] = 0.0f; f1[j] = 0.0f; }
        if (valid && g < 2) {
            const int s = ei[em], r = ei[E + em];
            if (g == 0) {
                const float4 a = *reinterpret_cast<const float4*>(hr  + 4 * (size_t)s);
                const float4 b = *reinterpret_cast<const float4*>(hr  + 4 * (size_t)r);
                const float4 c = *reinterpret_cast<const float4*>(hi_ + 4 * (size_t)s);
                const float4 d = *reinterpret_cast<const float4*>(hi_ + 4 * (size_t)r);
                f0[0] = a.x; f0[1] = a.y; f0[2] = a.z; f0[3] = a.w;
                f0[4] = b.x; f0[5] = b.y; f0[6] = b.z; f0[7] = b.w;
                f1[0] = c.x; f1[1] = c.y; f1[2] = c.z; f1[3] = c.w;
                f1[4] = d.x; f1[5] = d.y; f1[6] = d.z; f1[7] = d.w;
            } else {
                const float2 n0 = *reinterpret_cast<const float2*>(npar + 2 * (size_t)s);
                const float2 n1 = *reinterpret_cast<const float2*>(npar + 2 * (size_t)r);
                const float e0 = epar[ei[2 * em + 0]];
                const float e1 = epar[ei[2 * em + 1]];
                f0[0] = n0.x; f0[1] = n0.y; f0[2] = n1.x; f0[3] = n1.y;
                f0[4] = e0;   f0[5] = e1;
                #pragma unroll
                for (int j = 0; j < 6; ++j) f1[j] = f0[j];
            }
        }
        half8 xh0, xls0, xh1, xls1;
        #pragma unroll
        for (int j = 0; j < 8; ++j) {
            const _Float16 h0 = (_Float16)f0[j];
            xh0[j] = h0;
            xls0[j] = (_Float16)((f0[j] - (float)h0) * LO_SCALE);
            const _Float16 h1 = (_Float16)f1[j];
            xh1[j] = h1;
            xls1[j] = (_Float16)((f1[j] - (float)h1) * LO_SCALE);
        }

        // ---------- Layer 1 (both MLPs interleaved): (16x32) @ (32x64) ------
        #pragma unroll 2
        for (int nt = 0; nt < 4; ++nt) {
            const float bvR = br1v[nt], bvI = bi1v[nt];
            f32x4 amR = {bvR, bvR, bvR, bvR}, acR = {0.f, 0.f, 0.f, 0.f};
            f32x4 amI = {bvI, bvI, bvI, bvI}, acI = {0.f, 0.f, 0.f, 0.f};
            const half8 bhR = *reinterpret_cast<const half8*>(&whR[(nt * 64 + lane) * 8]);
            const half8 blR = *reinterpret_cast<const half8*>(&wlR[(nt * 64 + lane) * 8]);
            const half8 bhI = *reinterpret_cast<const half8*>(&whI[(nt * 64 + lane) * 8]);
            const half8 blI = *reinterpret_cast<const half8*>(&wlI[(nt * 64 + lane) * 8]);
            amR = MFMA16(xh0, bhR, amR);
            amI = MFMA16(xh1, bhI, amI);
            acR = MFMA16(xls0, bhR, acR);
            acI = MFMA16(xls1, bhI, acI);
            acR = MFMA16(xh0, blR, acR);
            acI = MFMA16(xh1, blI, acI);
            #pragma unroll
            for (int i = 0; i < 4; ++i) {
                const int off = (4 * g + i) * 72 + nt * 16 + m16;
                Hr[off] = (_Float16)silu_f(amR[i] + acR[i] * LO_INV);
                Hi[off] = (_Float16)silu_f(amI[i] + acI[i] * LO_INV);
            }
        }

        // ---------- Layer 2 (both MLPs): (16x64) @ (64x64) ----------
        {
            const half8 a0R = *reinterpret_cast<const half8*>(&Hr[m16 * 72 + 8 * g]);
            const half8 a1R = *reinterpret_cast<const half8*>(&Hr[m16 * 72 + 32 + 8 * g]);
            const half8 a0I = *reinterpret_cast<const half8*>(&Hi[m16 * 72 + 8 * g]);
            const half8 a1I = *reinterpret_cast<const half8*>(&Hi[m16 * 72 + 32 + 8 * g]);
            #pragma unroll 2
            for (int nt = 0; nt < 4; ++nt) {
                const float bvR = br2v[nt], bvI = bi2v[nt];
                f32x4 amR = {bvR, bvR, bvR, bvR}, acR = {0.f, 0.f, 0.f, 0.f};
                f32x4 amI = {bvI, bvI, bvI, bvI}, acI = {0.f, 0.f, 0.f, 0.f};
                const half8 bh0R = *reinterpret_cast<const half8*>(&whR[2048 + ((0 * 4 + nt) * 64 + lane) * 8]);
                const half8 bl0R = *reinterpret_cast<const half8*>(&wlR[2048 + ((0 * 4 + nt) * 64 + lane) * 8]);
                const half8 bh1R = *reinterpret_cast<const half8*>(&whR[2048 + ((1 * 4 + nt) * 64 + lane) * 8]);
                const half8 bl1R = *reinterpret_cast<const half8*>(&wlR[2048 + ((1 * 4 + nt) * 64 + lane) * 8]);
                const half8 bh0I = *reinterpret_cast<const half8*>(&whI[2048 + ((0 * 4 + nt) * 64 + lane) * 8]);
                const half8 bl0I = *reinterpret_cast<const half8*>(&wlI[2048 + ((0 * 4 + nt) * 64 + lane) * 8]);
                const half8 bh1I = *reinterpret_cast<const half8*>(&whI[2048 + ((1 * 4 + nt) * 64 + lane) * 8]);
                const half8 bl1I = *reinterpret_cast<const half8*>(&wlI[2048 + ((1 * 4 + nt) * 64 + lane) * 8]);
                amR = MFMA16(a0R, bh0R, amR);
                amI = MFMA16(a0I, bh0I, amI);
                amR = MFMA16(a1R, bh1R, amR);
                amI = MFMA16(a1I, bh1I, amI);
                acR = MFMA16(a0R, bl0R, acR);
                acI = MFMA16(a0I, bl0I, acI);
                acR = MFMA16(a1R, bl1R, acR);
                acI = MFMA16(a1I, bl1I, acI);
                #pragma unroll
                for (int i = 0; i < 4; ++i) {
                    const int off = (4 * g + i) * 72 + nt * 16 + m16;
                    Hr[off] = (_Float16)silu_f(amR[i] + acR[i] * LO_INV);  // a-frags in regs
                    Hi[off] = (_Float16)silu_f(amI[i] + acI[i] * LO_INV);
                }
            }
        }

        // ---------- Layer 3 (both MLPs): (16x64) @ (64x16), 4 valid cols ----
        {
            const half8 a0R = *reinterpret_cast<const half8*>(&Hr[m16 * 72 + 8 * g]);
            const half8 a1R = *reinterpret_cast<const half8*>(&Hr[m16 * 72 + 32 + 8 * g]);
            const half8 a0I = *reinterpret_cast<const half8*>(&Hi[m16 * 72 + 8 * g]);
            const half8 a1I = *reinterpret_cast<const half8*>(&Hi[m16 * 72 + 32 + 8 * g]);
            f32x4 amR = {br3v, br3v, br3v, br3v}, acR = {0.f, 0.f, 0.f, 0.f};
            f32x4 amI = {bi3v, bi3v, bi3v, bi3v}, acI = {0.f, 0.f, 0.f, 0.f};
            const half8 bh0R = *reinterpret_cast<const half8*>(&whR[6144 + (0 * 64 + lane) * 8]);
            const half8 bl0R = *reinterpret_cast<const half8*>(&wlR[6144 + (0 * 64 + lane) * 8]);
            const half8 bh1R = *reinterpret_cast<const half8*>(&whR[6144 + (1 * 64 + lane) * 8]);
            const half8 bl1R = *reinterpret_cast<const half8*>(&wlR[6144 + (1 * 64 + lane) * 8]);
            const half8 bh0I = *reinterpret_cast<const half8*>(&whI[6144 + (0 * 64 + lane) * 8]);
            const half8 bl0I = *reinterpret_cast<const half8*>(&wlI[6144 + (0 * 64 + lane) * 8]);
            const half8 bh1I = *reinterpret_cast<const half8*>(&whI[6144 + (1 * 64 + lane) * 8]);
            const half8 bl1I = *reinterpret_cast<const half8*>(&wlI[6144 + (1 * 64 + lane) * 8]);
            amR = MFMA16(a0R, bh0R, amR);
            amI = MFMA16(a0I, bh0I, amI);
            amR = MFMA16(a1R, bh1R, amR);
            amI = MFMA16(a1I, bh1I, amI);
            acR = MFMA16(a0R, bl0R, acR);
            acI = MFMA16(a0I, bl0I, acI);
            acR = MFMA16(a1R, bl1R, acR);
            acI = MFMA16(a1I, bl1I, acI);
            if (m16 < 4) {
                #pragma unroll
                for (int i = 0; i < 4; ++i) {
                    H3[(4 * g + i) * 8 + m16 + 0] = amR[i] + acR[i] * LO_INV;
                    H3[(4 * g + i) * 8 + m16 + 4] = amI[i] + acI[i] * LO_INV;
                }
            }
        }

        // ---- epilogue: 16 lanes, one edge each (wave-internal LDS, no barrier)
        if (lane < 16) {
            const int e2 = tile * 16 + lane;
            if (e2 < E) {
                const float4 Ai4 = *reinterpret_cast<const float4*>(&H3[lane * 8 + 4]);
                const float4 Ar4 = *reinterpret_cast<const float4*>(&H3[lane * 8 + 0]);
                const float Ai[4] = {Ai4.x, Ai4.y, Ai4.z, Ai4.w};
                const float Ar[4] = {Ar4.x, Ar4.y, Ar4.z, Ar4.w};
                const int r = ei[E + e2];
                #pragma unroll
                for (int t = 0; t < 3; ++t) {
                    float z = bav[t];
                    #pragma unroll
                    for (int j = 0; j < 4; ++j) z += Ai[j] * wav[j * 3 + t];
                    #pragma unroll
                    for (int j = 0; j < 4; ++j) z += Ar[j] * wav[(4 + j) * 3 + t];
                    atomicAdd(aggout + (size_t)stride * (size_t)r + t, tanh_f(z) * PI_F);
                }
            }
        }
    }
}

// ---------------- round-6 scalar fallback (ws too small) ----------------
__device__ __forceinline__ void mlp14_64_64_4(
    const float x[14],
    const float* __restrict__ W1, const float* __restrict__ b1,
    const float* __restrict__ W2, const float* __restrict__ b2,
    const float* __restrict__ W3, const float* __restrict__ b3,
    float A[4])
{
    float h1[64];
    #pragma unroll
    for (int j = 0; j < 64; ++j) h1[j] = b1[j];
    #pragma unroll
    for (int k = 0; k < 14; ++k) {
        const float xk = x[k];
        #pragma unroll
        for (int j = 0; j < 64; ++j) h1[j] += xk * W1[k * 64 + j];
    }
    #pragma unroll
    for (int j = 0; j < 64; ++j) h1[j] = silu_f(h1[j]);
    float h2[64];
    #pragma unroll
    for (int j = 0; j < 64; ++j) h2[j] = b2[j];
    #pragma unroll
    for (int k = 0; k < 64; ++k) {
        const float hk = h1[k];
        #pragma unroll
        for (int j = 0; j < 64; ++j) h2[j] += hk * W2[k * 64 + j];
    }
    #pragma unroll
    for (int j = 0; j < 64; ++j) h2[j] = silu_f(h2[j]);
    float a0 = b3[0], a1 = b3[1], a2 = b3[2], a3 = b3[3];
    #pragma unroll
    for (int k = 0; k < 64; ++k) {
        const float hk = h2[k];
        a0 += hk * W3[k * 4 + 0];
        a1 += hk * W3[k * 4 + 1];
        a2 += hk * W3[k * 4 + 2];
        a3 += hk * W3[k * 4 + 3];
    }
    A[0] = a0; A[1] = a1; A[2] = a2; A[3] = a3;
}

template<int STRIDE>
__global__ __launch_bounds__(256) void qgnn_edge_kernel(
    const float* __restrict__ hr, const float* __restrict__ hi,
    const int* __restrict__ ei,
    const float* __restrict__ npar, const float* __restrict__ epar,
    const float* __restrict__ Wa, const float* __restrict__ ba,
    const float* __restrict__ Wr1, const float* __restrict__ br1,
    const float* __restrict__ Wr2, const float* __restrict__ br2,
    const float* __restrict__ Wr3, const float* __restrict__ br3,
    const float* __restrict__ Wi1, const float* __restrict__ bi1,
    const float* __restrict__ Wi2, const float* __restrict__ bi2,
    const float* __restrict__ Wi3, const float* __restrict__ bi3,
    float* __restrict__ aggout, int E)
{
    const int e = blockIdx.x * blockDim.x + threadIdx.x;
    if (e >= E) return;
    const int s = ei[e];
    const int r = ei[E + e];
    const float ep0 = epar[ei[2 * e + 0]];
    const float ep1 = epar[ei[2 * e + 1]];
    const float4 hrs = *reinterpret_cast<const float4*>(hr + 4 * (size_t)s);
    const float4 hrr = *reinterpret_cast<const float4*>(hr + 4 * (size_t)r);
    const float2 nps = *reinterpret_cast<const float2*>(npar + 2 * (size_t)s);
    const float2 npr = *reinterpret_cast<const float2*>(npar + 2 * (size_t)r);
    float x[14];
    x[0] = hrs.x; x[1] = hrs.y; x[2] = hrs.z; x[3] = hrs.w;
    x[4] = hrr.x; x[5] = hrr.y; x[6] = hrr.z; x[7] = hrr.w;
    x[8] = nps.x; x[9] = nps.y; x[10] = npr.x; x[11] = npr.y;
    x[12] = ep0;  x[13] = ep1;
    float Ar[4];
    mlp14_64_64_4(x, Wr1, br1, Wr2, br2, Wr3, br3, Ar);
    const float4 his = *reinterpret_cast<const float4*>(hi + 4 * (size_t)s);
    const float4 hir = *reinterpret_cast<const float4*>(hi + 4 * (size_t)r);
    x[0] = his.x; x[1] = his.y; x[2] = his.z; x[3] = his.w;
    x[4] = hir.x; x[5] = hir.y; x[6] = hir.z; x[7] = hir.w;
    float Ai[4];
    mlp14_64_64_4(x, Wi1, bi1, Wi2, bi2, Wi3, bi3, Ai);
    #pragma unroll
    for (int t = 0; t < 3; ++t) {
        float z = ba[t];
        #pragma unroll
        for (int j = 0; j < 4; ++j) z += Ai[j] * Wa[j * 3 + t];
        #pragma unroll
        for (int j = 0; j < 4; ++j) z += Ar[j] * Wa[(4 + j) * 3 + t];
        atomicAdd(aggout + (size_t)STRIDE * (size_t)r + t, tanh_f(z) * PI_F);
    }
}

// ---------------- node kernel ----------------
__device__ __forceinline__ float wrap_pi(float v) {
    float rm = fmodf(v + PI_F, TWO_PI_F);
    if (rm < 0.0f) rm += TWO_PI_F;
    return rm - PI_F;
}

template<int STRIDE, bool WRITE_COMPLEX>
__global__ __launch_bounds__(256) void qgnn_node_kernel(
    const float* __restrict__ hr,
    const float* __restrict__ hi,
    float* __restrict__ out, int N)
{
    const int n = blockIdx.x * blockDim.x + threadIdx.x;
    if (n >= N) return;
    const float a = wrap_pi(out[(size_t)STRIDE * n + 0]);
    const float b = wrap_pi(out[(size_t)STRIDE * n + 1]);
    const float c = wrap_pi(out[(size_t)STRIDE * n + 2]);
    const float cb = __cosf(0.5f * b);
    const float sb = __sinf(0.5f * b);
    const float hpc = 0.5f * (a + c);
    const float hmc = 0.5f * (a - c);
    const float cpc = __cosf(hpc), spc = __sinf(hpc);
    const float cmc = __cosf(hmc), smc = __sinf(hmc);
    float Ur[2][2], Ui[2][2];
    Ur[0][0] =  cpc * cb;  Ui[0][0] = -spc * cb;
    Ur[0][1] = -cmc * sb;  Ui[0][1] =  smc * sb;
    Ur[1][0] =  cmc * sb;  Ui[1][0] =  smc * sb;
    Ur[1][1] =  cpc * cb;  Ui[1][1] =  spc * cb;
    const float4 h4r = *reinterpret_cast<const float4*>(hr + 4 * (size_t)n);
    const float4 h4i = *reinterpret_cast<const float4*>(hi + 4 * (size_t)n);
    float Hr[2][2] = {{h4r.x, h4r.y}, {h4r.z, h4r.w}};
    float Hi[2][2] = {{h4i.x, h4i.y}, {h4i.z, h4i.w}};
    float Tr[2][2], Ti[2][2];
    #pragma unroll
    for (int p = 0; p < 2; ++p) {
        #pragma unroll
        for (int j = 0; j < 2; ++j) {
            float tr = 0.0f, ti = 0.0f;
            #pragma unroll
            for (int t = 0; t < 2; ++t) {
                tr += Hr[p][t] * Ur[j][t] + Hi[p][t] * Ui[j][t];
                ti += Hi[p][t] * Ur[j][t] - Hr[p][t] * Ui[j][t];
            }
            Tr[p][j] = tr; Ti[p][j] = ti;
        }
    }
    float orr[2][2], oii[2][2];
    #pragma unroll
    for (int i = 0; i < 2; ++i) {
        #pragma unroll
        for (int j = 0; j < 2; ++j) {
            float xr = 0.0f, xi = 0.0f;
            #pragma unroll
            for (int p = 0; p < 2; ++p) {
                xr += Ur[i][p] * Tr[p][j] - Ui[i][p] * Ti[p][j];
                xi += Ur[i][p] * Ti[p][j] + Ui[i][p] * Tr[p][j];
            }
            orr[i][j] = xr; oii[i][j] = xi;
        }
    }
    if (WRITE_COMPLEX) {
        float4* outv = reinterpret_cast<float4*>(out + (size_t)STRIDE * n);
        outv[0] = make_float4(orr[0][0], oii[0][0], orr[0][1], oii[0][1]);
        outv[1] = make_float4(orr[1][0], oii[1][0], orr[1][1], oii[1][1]);
    } else {
        *reinterpret_cast<float4*>(out + (size_t)STRIDE * n) =
            make_float4(orr[0][0], orr[0][1], orr[1][0], orr[1][1]);
    }
}

extern "C" void kernel_launch(void* const* d_in, const int* in_sizes, int n_in,
                              void* d_out, int out_size, void* d_ws, size_t ws_size,
                              hipStream_t stream) {
    const float* hr   = (const float*)d_in[0];
    const float* hi   = (const float*)d_in[1];
    const int*   ei   = (const int*)  d_in[2];
    const float* npar = (const float*)d_in[3];
    const float* epar = (const float*)d_in[4];
    const float* Wa  = (const float*)d_in[5];
    const float* ba  = (const float*)d_in[6];
    const float* Wr1 = (const float*)d_in[7];
    const float* br1 = (const float*)d_in[8];
    const float* Wr2 = (const float*)d_in[9];
    const float* br2 = (const float*)d_in[10];
    const float* Wr3 = (const float*)d_in[11];
    const float* br3 = (const float*)d_in[12];
    const float* Wi1 = (const float*)d_in[13];
    const float* bi1 = (const float*)d_in[14];
    const float* Wi2 = (const float*)d_in[15];
    const float* bi2 = (const float*)d_in[16];
    const float* Wi3 = (const float*)d_in[17];
    const float* bi3 = (const float*)d_in[18];

    const int N = in_sizes[0] / 4;   // h_i_real is (N,2,2)
    const int E = in_sizes[2] / 2;   // edge_index is (2,E)

    float* out = (float*)d_out;
    const bool cplx = (out_size >= 8 * N);
    const int stride = cplx ? 8 : 4;
    const int total = stride * N;
    qgnn_zero_kernel<<<(total + 255) / 256, 256, 0, stream>>>(out, total);

    const bool use_mfma = (ws_size >= (size_t)WS_BYTES_NEEDED);
    if (use_mfma) {
        qgnn_prep_kernel<<<56, 256, 0, stream>>>(Wr1, Wr2, Wr3, Wi1, Wi2, Wi3,
                                                 (unsigned short*)d_ws);
        const int ntiles = (E + 15) / 16;
        int blocks = (ntiles + NW - 1) / NW;
        if (blocks > 4096) blocks = 4096;
        qgnn_edge_mfma_kernel<<<blocks, 256, 0, stream>>>(
            hr, hi, ei, npar, epar, Wa, ba,
            br1, br2, br3, bi1, bi2, bi3,
            (const unsigned short*)d_ws, out, E, stride);
    } else if (cplx) {
        qgnn_edge_kernel<8><<<(E + 255) / 256, 256, 0, stream>>>(
            hr, hi, ei, npar, epar, Wa, ba,
            Wr1, br1, Wr2, br2, Wr3, br3,
            Wi1, bi1, Wi2, bi2, Wi3, bi3, out, E);
    } else {
        qgnn_edge_kernel<4><<<(E + 255) / 256, 256, 0, stream>>>(
            hr, hi, ei, npar, epar, Wa, ba,
            Wr1, br1, Wr2, br2, Wr3, br3,
            Wi1, bi1, Wi2, bi2, Wi3, bi3, out, E);
    }

    if (cplx) {
        qgnn_node_kernel<8, true><<<(N + 255) / 256, 256, 0, stream>>>(hr, hi, out, N);
    } else {
        qgnn_node_kernel<4, false><<<(N + 255) / 256, 256, 0, stream>>>(hr, hi, out, N);
    }
}

// Round 21
// 296.640 us; speedup vs baseline: 1.0306x; 1.0306x over previous
//
// Round 21 = round 20 resubmitted verbatim (r20 died on UnresponsiveContainer
// from the recurring flaky pod; no compile/run occurred).
// Experiment: r19's M=2 with the H-stride bug fixed (RS 40 -> 72). r19's NaN
// was a buffer overflow: H is [32 rows][64 cols] but stride was 40 -> rows
// overlapped and writes spilled past the per-wave slice. Max index now
// 31*72+63=2295 < 2304. LDS 51200 B -> 3 blocks/CU. M=2 (32 edges/wave/tile)
// amortizes tile-invariant weight loads; L1 bias folded into weight row k=14
// (x[14]=1.0); deferred L2/L3 bias.
#include <hip/hip_runtime.h>

#define PI_F     3.14159265358979323846f
#define TWO_PI_F 6.28318530717958647692f

typedef __attribute__((ext_vector_type(8))) _Float16 half8;
typedef __attribute__((ext_vector_type(4))) float f32x4;

#define LO_SCALE   2048.0f
#define LO_INV     (1.0f / 2048.0f)
#define RS 72   // H row stride in halfs (64 cols + 8 pad)

__device__ __forceinline__ float fast_rcp(float x) { return __builtin_amdgcn_rcpf(x); }
__device__ __forceinline__ float silu_f(float v) { return v * fast_rcp(1.0f + __expf(-v)); }
__device__ __forceinline__ float tanh_f(float z) {
    float ez = __expf(2.0f * z);
    return 1.0f - 2.0f * fast_rcp(ez + 1.0f);
}

// ---------------- prep: fragment-ordered fp16 hi / scaled-lo weight planes --
// Layout as r8-r18; L1 row k==14 carries the layer-1 bias (consumed by
// x[14]=1.0 in the gather), rows 15..31 remain zero.
#define WS_U16_TOTAL 28672
#define WS_BYTES_NEEDED (WS_U16_TOTAL * 2)
#define W_HI_U16 14336

__global__ __launch_bounds__(256) void qgnn_prep_kernel(
    const float* __restrict__ Wr1, const float* __restrict__ Wr2, const float* __restrict__ Wr3,
    const float* __restrict__ Wi1, const float* __restrict__ Wi2, const float* __restrict__ Wi3,
    const float* __restrict__ br1, const float* __restrict__ bi1,
    unsigned short* __restrict__ wsu)
{
    int idx = blockIdx.x * 256 + threadIdx.x;
    if (idx >= 14336) return;
    int rel = idx;
    int half = (rel >= 7168);
    if (half) rel -= 7168;
    const float* W; int base, NT, Kr, Nr; bool isL1 = false;
    if (rel < 2048)      { W = half ? Wi1 : Wr1; base = 0;    NT = 4; Kr = 14; Nr = 64; isL1 = true; }
    else if (rel < 6144) { W = half ? Wi2 : Wr2; base = 2048; NT = 4; Kr = 64; Nr = 64; }
    else                 { W = half ? Wi3 : Wr3; base = 6144; NT = 1; Kr = 64; Nr = 4;  }
    int f = rel - base;
    int frag = f >> 9, rem = f & 511;
    int l = rem >> 3, j = rem & 7;
    int nt = frag % NT, kt = frag / NT;
    int k = kt * 32 + ((l >> 4) << 3) + j;
    int n = nt * 16 + (l & 15);
    float v = 0.0f;
    if (k < Kr && n < Nr) v = W[k * Nr + n];
    else if (isL1 && k == 14) v = (half ? bi1 : br1)[n];   // bias row (x[14]=1)
    _Float16 hi = (_Float16)v;                                  // RNE
    _Float16 lo = (_Float16)((v - (float)hi) * LO_SCALE);       // scaled residual
    wsu[idx] = *reinterpret_cast<unsigned short*>(&hi);
    wsu[14336 + idx] = *reinterpret_cast<unsigned short*>(&lo);
}

__global__ __launch_bounds__(256) void qgnn_zero_kernel(float* __restrict__ p, int n) {
    const int i = blockIdx.x * blockDim.x + threadIdx.x;
    if (i < n) p[i] = 0.0f;
}

#define MFMA16(a, b, c) __builtin_amdgcn_mfma_f32_16x16x32_f16((a), (b), (c), 0, 0, 0)
#define NW 4   // waves per block

// One MLP over 32 edges (halves A,B): X -> 64 -> 64 -> 4.
// L1 bias lives in weight row 14; L2/L3 bias deferred (added post-MFMA).
__device__ __forceinline__ void run_mlp2(
    half8 ahA, half8 alsA, half8 ahB, half8 alsB,
    const _Float16* __restrict__ wh,
    const unsigned short* __restrict__ wls,
    f32x4 b2v, float b3v,
    _Float16* __restrict__ H, float* __restrict__ h3out,
    int lane, int m16, int g)
{
    const f32x4 ZERO4 = {0.f, 0.f, 0.f, 0.f};

    // ---------- Layer 1: (32x32) @ (32x64), bias in weights ----------
    #pragma unroll 2
    for (int nt = 0; nt < 4; ++nt) {
        const half8 bh = *reinterpret_cast<const half8*>(&wh[(nt * 64 + lane) * 8]);
        const half8 bl = *reinterpret_cast<const half8*>(&wls[(nt * 64 + lane) * 8]);
        f32x4 amA = MFMA16(ahA, bh, ZERO4);
        f32x4 acA = MFMA16(alsA, bh, ZERO4);
        acA = MFMA16(ahA, bl, acA);
        f32x4 amB = MFMA16(ahB, bh, ZERO4);
        f32x4 acB = MFMA16(alsB, bh, ZERO4);
        acB = MFMA16(ahB, bl, acB);
        #pragma unroll
        for (int i = 0; i < 4; ++i) {
            const int col = nt * 16 + m16;
            H[(4 * g + i) * RS + col]        = (_Float16)silu_f(amA[i] + acA[i] * LO_INV);
            H[(16 + 4 * g + i) * RS + col]   = (_Float16)silu_f(amB[i] + acB[i] * LO_INV);
        }
    }

    // ---------- Layer 2: (32x64) @ (64x64), deferred bias ----------
    {
        const half8 a0A = *reinterpret_cast<const half8*>(&H[m16 * RS + 8 * g]);
        const half8 a1A = *reinterpret_cast<const half8*>(&H[m16 * RS + 32 + 8 * g]);
        const half8 a0B = *reinterpret_cast<const half8*>(&H[(16 + m16) * RS + 8 * g]);
        const half8 a1B = *reinterpret_cast<const half8*>(&H[(16 + m16) * RS + 32 + 8 * g]);
        #pragma unroll 1
        for (int nt = 0; nt < 4; ++nt) {
            const half8 bh0 = *reinterpret_cast<const half8*>(&wh[2048 + ((0 * 4 + nt) * 64 + lane) * 8]);
            const half8 bl0 = *reinterpret_cast<const half8*>(&wls[2048 + ((0 * 4 + nt) * 64 + lane) * 8]);
            const half8 bh1 = *reinterpret_cast<const half8*>(&wh[2048 + ((1 * 4 + nt) * 64 + lane) * 8]);
            const half8 bl1 = *reinterpret_cast<const half8*>(&wls[2048 + ((1 * 4 + nt) * 64 + lane) * 8]);
            f32x4 amA = MFMA16(a0A, bh0, ZERO4);
            amA = MFMA16(a1A, bh1, amA);
            f32x4 acA = MFMA16(a0A, bl0, ZERO4);
            acA = MFMA16(a1A, bl1, acA);
            f32x4 amB = MFMA16(a0B, bh0, ZERO4);
            amB = MFMA16(a1B, bh1, amB);
            f32x4 acB = MFMA16(a0B, bl0, ZERO4);
            acB = MFMA16(a1B, bl1, acB);
            const float bv = b2v[nt];
            #pragma unroll
            for (int i = 0; i < 4; ++i) {
                const int col = nt * 16 + m16;
                H[(4 * g + i) * RS + col]      = (_Float16)silu_f(amA[i] + acA[i] * LO_INV + bv);
                H[(16 + 4 * g + i) * RS + col] = (_Float16)silu_f(amB[i] + acB[i] * LO_INV + bv);
            }
        }
    }

    // ---------- Layer 3: (32x64) @ (64x16), 4 valid cols ----------
    {
        const half8 a0A = *reinterpret_cast<const half8*>(&H[m16 * RS + 8 * g]);
        const half8 a1A = *reinterpret_cast<const half8*>(&H[m16 * RS + 32 + 8 * g]);
        const half8 a0B = *reinterpret_cast<const half8*>(&H[(16 + m16) * RS + 8 * g]);
        const half8 a1B = *reinterpret_cast<const half8*>(&H[(16 + m16) * RS + 32 + 8 * g]);
        const half8 bh0 = *reinterpret_cast<const half8*>(&wh[6144 + (0 * 64 + lane) * 8]);
        const half8 bl0 = *reinterpret_cast<const half8*>(&wls[6144 + (0 * 64 + lane) * 8]);
        const half8 bh1 = *reinterpret_cast<const half8*>(&wh[6144 + (1 * 64 + lane) * 8]);
        const half8 bl1 = *reinterpret_cast<const half8*>(&wls[6144 + (1 * 64 + lane) * 8]);
        f32x4 amA = MFMA16(a0A, bh0, ZERO4);
        amA = MFMA16(a1A, bh1, amA);
        f32x4 acA = MFMA16(a0A, bl0, ZERO4);
        acA = MFMA16(a1A, bl1, acA);
        f32x4 amB = MFMA16(a0B, bh0, ZERO4);
        amB = MFMA16(a1B, bh1, amB);
        f32x4 acB = MFMA16(a0B, bl0, ZERO4);
        acB = MFMA16(a1B, bl1, acB);
        if (m16 < 4) {
            #pragma unroll
            for (int i = 0; i < 4; ++i) {
                h3out[(4 * g + i) * 8 + m16]        = amA[i] + acA[i] * LO_INV + b3v;
                h3out[(16 + 4 * g + i) * 8 + m16]   = amB[i] + acB[i] * LO_INV + b3v;
            }
        }
    }
}

__global__ __launch_bounds__(256, 3) void qgnn_edge_mfma_kernel(
    const float* __restrict__ hr, const float* __restrict__ hi_,
    const int* __restrict__ ei,
    const float* __restrict__ npar, const float* __restrict__ epar,
    const float* __restrict__ Wa, const float* __restrict__ ba,
    const float* __restrict__ br2, const float* __restrict__ br3,
    const float* __restrict__ bi2, const float* __restrict__ bi3,
    const unsigned short* __restrict__ wsu,
    float* __restrict__ aggout, int E, int stride)
{
    __shared__ __align__(16) _Float16 sW[W_HI_U16];            // 28672 B (hi plane)
    __shared__ __align__(16) _Float16 sH[NW][32 * RS];         // 4x4608 B
    __shared__ __align__(16) float sH3[NW][32 * 8];            // 4x1024 B
    // total 51200 B -> 3 blocks/CU

    // ---- stage hi-plane weights once (the only barrier in this kernel) ----
    {
        unsigned short* sWu = reinterpret_cast<unsigned short*>(sW);
        for (int o = threadIdx.x * 8; o < W_HI_U16; o += 256 * 8)
            *reinterpret_cast<uint4*>(sWu + o) = *reinterpret_cast<const uint4*>(wsu + o);
    }
    __syncthreads();

    const int tid = threadIdx.x, w = tid >> 6, lane = tid & 63;
    const int m16 = lane & 15, g = lane >> 4;
    _Float16* H = sH[w];
    float* H3 = sH3[w];

    // ---- per-lane constants (registers) ----
    f32x4 br2v, bi2v;
    #pragma unroll
    for (int q = 0; q < 4; ++q) {
        br2v[q] = br2[q * 16 + m16];
        bi2v[q] = bi2[q * 16 + m16];
    }
    const float br3v = (m16 < 4) ? br3[m16] : 0.0f;
    const float bi3v = (m16 < 4) ? bi3[m16] : 0.0f;
    float wav[24], bav[3];
    #pragma unroll
    for (int q = 0; q < 24; ++q) wav[q] = Wa[q];
    #pragma unroll
    for (int q = 0; q < 3; ++q) bav[q] = ba[q];

    const _Float16*       whR = sW;
    const _Float16*       whI = sW + 7168;
    const unsigned short* wlR = wsu + W_HI_U16;
    const unsigned short* wlI = wsu + W_HI_U16 + 7168;

    const int ntiles = (E + 31) >> 5;
    for (int tile = blockIdx.x * NW + w; tile < ntiles; tile += gridDim.x * NW) {
        // ---- gather X for both 16-edge halves into registers ----
        half8 xh0A, xls0A, xh1A, xls1A, xh0B, xls0B, xh1B, xls1B;
        #pragma unroll
        for (int hb = 0; hb < 2; ++hb) {
            const int em = tile * 32 + hb * 16 + m16;
            const bool valid = (em < E);
            float f0[8], f1[8];
            #pragma unroll
            for (int j = 0; j < 8; ++j) { f0[j] = 0.0f; f1[j] = 0.0f; }
            if (valid && g < 2) {
                const int s = ei[em], r = ei[E + em];
                if (g == 0) {
                    const float4 a = *reinterpret_cast<const float4*>(hr  + 4 * (size_t)s);
                    const float4 b = *reinterpret_cast<const float4*>(hr  + 4 * (size_t)r);
                    const float4 c = *reinterpret_cast<const float4*>(hi_ + 4 * (size_t)s);
                    const float4 d = *reinterpret_cast<const float4*>(hi_ + 4 * (size_t)r);
                    f0[0] = a.x; f0[1] = a.y; f0[2] = a.z; f0[3] = a.w;
                    f0[4] = b.x; f0[5] = b.y; f0[6] = b.z; f0[7] = b.w;
                    f1[0] = c.x; f1[1] = c.y; f1[2] = c.z; f1[3] = c.w;
                    f1[4] = d.x; f1[5] = d.y; f1[6] = d.z; f1[7] = d.w;
                } else {
                    const float2 n0 = *reinterpret_cast<const float2*>(npar + 2 * (size_t)s);
                    const float2 n1 = *reinterpret_cast<const float2*>(npar + 2 * (size_t)r);
                    const float e0 = epar[ei[2 * em + 0]];
                    const float e1 = epar[ei[2 * em + 1]];
                    // k = 8..15: np_s, np_r, ep0, ep1, [k=14] 1.0 (bias row), 0
                    f0[0] = n0.x; f0[1] = n0.y; f0[2] = n1.x; f0[3] = n1.y;
                    f0[4] = e0;   f0[5] = e1;   f0[6] = 1.0f;
                    #pragma unroll
                    for (int j = 0; j < 7; ++j) f1[j] = f0[j];
                }
            }
            half8 xh0, xls0, xh1, xls1;
            #pragma unroll
            for (int j = 0; j < 8; ++j) {
                const _Float16 h0 = (_Float16)f0[j];
                xh0[j] = h0;
                xls0[j] = (_Float16)((f0[j] - (float)h0) * LO_SCALE);
                const _Float16 h1 = (_Float16)f1[j];
                xh1[j] = h1;
                xls1[j] = (_Float16)((f1[j] - (float)h1) * LO_SCALE);
            }
            if (hb == 0) { xh0A = xh0; xls0A = xls0; xh1A = xh1; xls1A = xls1; }
            else         { xh0B = xh0; xls0B = xls0; xh1B = xh1; xls1B = xls1; }
        }

        run_mlp2(xh0A, xls0A, xh0B, xls0B, whR, wlR, br2v, br3v, H, H3 + 0, lane, m16, g);
        run_mlp2(xh1A, xls1A, xh1B, xls1B, whI, wlI, bi2v, bi3v, H, H3 + 4, lane, m16, g);

        // ---- epilogue: 32 lanes, one edge each (wave-internal LDS) ----
        if (lane < 32) {
            const int e2 = tile * 32 + lane;
            if (e2 < E) {
                const float4 Ar4 = *reinterpret_cast<const float4*>(&H3[lane * 8 + 0]);
                const float4 Ai4 = *reinterpret_cast<const float4*>(&H3[lane * 8 + 4]);
                const float Ar[4] = {Ar4.x, Ar4.y, Ar4.z, Ar4.w};
                const float Ai[4] = {Ai4.x, Ai4.y, Ai4.z, Ai4.w};
                const int r = ei[E + e2];
                #pragma unroll
                for (int t = 0; t < 3; ++t) {
                    float z = bav[t];
                    #pragma unroll
                    for (int j = 0; j < 4; ++j) z += Ai[j] * wav[j * 3 + t];
                    #pragma unroll
                    for (int j = 0; j < 4; ++j) z += Ar[j] * wav[(4 + j) * 3 + t];
                    atomicAdd(aggout + (size_t)stride * (size_t)r + t, tanh_f(z) * PI_F);
                }
            }
        }
    }
}

// ---------------- round-6 scalar fallback (ws too small) ----------------
__device__ __forceinline__ void mlp14_64_64_4(
    const float x[14],
    const float* __restrict__ W1, const float* __restrict__ b1,
    const float* __restrict__ W2, const float* __restrict__ b2,
    const float* __restrict__ W3, const float* __restrict__ b3,
    float A[4])
{
    float h1[64];
    #pragma unroll
    for (int j = 0; j < 64; ++j) h1[j] = b1[j];
    #pragma unroll
    for (int k = 0; k < 14; ++k) {
        const float xk = x[k];
        #pragma unroll
        for (int j = 0; j < 64; ++j) h1[j] += xk * W1[k * 64 + j];
    }
    #pragma unroll
    for (int j = 0; j < 64; ++j) h1[j] = silu_f(h1[j]);
    float h2[64];
    #pragma unroll
    for (int j = 0; j < 64; ++j) h2[j] = b2[j];
    #pragma unroll
    for (int k = 0; k < 64; ++k) {
        const float hk = h1[k];
        #pragma unroll
        for (int j = 0; j < 64; ++j) h2[j] += hk * W2[k * 64 + j];
    }
    #pragma unroll
    for (int j = 0; j < 64; ++j) h2[j] = silu_f(h2[j]);
    float a0 = b3[0], a1 = b3[1], a2 = b3[2], a3 = b3[3];
    #pragma unroll
    for (int k = 0; k < 64; ++k) {
        const float hk = h2[k];
        a0 += hk * W3[k * 4 + 0];
        a1 += hk * W3[k * 4 + 1];
        a2 += hk * W3[k * 4 + 2];
        a3 += hk * W3[k * 4 + 3];
    }
    A[0] = a0; A[1] = a1; A[2] = a2; A[3] = a3;
}

template<int STRIDE>
__global__ __launch_bounds__(256) void qgnn_edge_kernel(
    const float* __restrict__ hr, const float* __restrict__ hi,
    const int* __restrict__ ei,
    const float* __restrict__ npar, const float* __restrict__ epar,
    const float* __restrict__ Wa, const float* __restrict__ ba,
    const float* __restrict__ Wr1, const float* __restrict__ br1,
    const float* __restrict__ Wr2, const float* __restrict__ br2,
    const float* __restrict__ Wr3, const float* __restrict__ br3,
    const float* __restrict__ Wi1, const float* __restrict__ bi1,
    const float* __restrict__ Wi2, const float* __restrict__ bi2,
    const float* __restrict__ Wi3, const float* __restrict__ bi3,
    float* __restrict__ aggout, int E)
{
    const int e = blockIdx.x * blockDim.x + threadIdx.x;
    if (e >= E) return;
    const int s = ei[e];
    const int r = ei[E + e];
    const float ep0 = epar[ei[2 * e + 0]];
    const float ep1 = epar[ei[2 * e + 1]];
    const float4 hrs = *reinterpret_cast<const float4*>(hr + 4 * (size_t)s);
    const float4 hrr = *reinterpret_cast<const float4*>(hr + 4 * (size_t)r);
    const float2 nps = *reinterpret_cast<const float2*>(npar + 2 * (size_t)s);
    const float2 npr = *reinterpret_cast<const float2*>(npar + 2 * (size_t)r);
    float x[14];
    x[0] = hrs.x; x[1] = hrs.y; x[2] = hrs.z; x[3] = hrs.w;
    x[4] = hrr.x; x[5] = hrr.y; x[6] = hrr.z; x[7] = hrr.w;
    x[8] = nps.x; x[9] = nps.y; x[10] = npr.x; x[11] = npr.y;
    x[12] = ep0;  x[13] = ep1;
    float Ar[4];
    mlp14_64_64_4(x, Wr1, br1, Wr2, br2, Wr3, br3, Ar);
    const float4 his = *reinterpret_cast<const float4*>(hi + 4 * (size_t)s);
    const float4 hir = *reinterpret_cast<const float4*>(hi + 4 * (size_t)r);
    x[0] = his.x; x[1] = his.y; x[2] = his.z; x[3] = his.w;
    x[4] = hir.x; x[5] = hir.y; x[6] = hir.z; x[7] = hir.w;
    float Ai[4];
    mlp14_64_64_4(x, Wi1, bi1, Wi2, bi2, Wi3, bi3, Ai);
    #pragma unroll
    for (int t = 0; t < 3; ++t) {
        float z = ba[t];
        #pragma unroll
        for (int j = 0; j < 4; ++j) z += Ai[j] * Wa[j * 3 + t];
        #pragma unroll
        for (int j = 0; j < 4; ++j) z += Ar[j] * Wa[(4 + j) * 3 + t];
        atomicAdd(aggout + (size_t)STRIDE * (size_t)r + t, tanh_f(z) * PI_F);
    }
}

// ---------------- node kernel ----------------
__device__ __forceinline__ float wrap_pi(float v) {
    float rm = fmodf(v + PI_F, TWO_PI_F);
    if (rm < 0.0f) rm += TWO_PI_F;
    return rm - PI_F;
}

template<int STRIDE, bool WRITE_COMPLEX>
__global__ __launch_bounds__(256) void qgnn_node_kernel(
    const float* __restrict__ hr,
    const float* __restrict__ hi,
    float* __restrict__ out, int N)
{
    const int n = blockIdx.x * blockDim.x + threadIdx.x;
    if (n >= N) return;
    const float a = wrap_pi(out[(size_t)STRIDE * n + 0]);
    const float b = wrap_pi(out[(size_t)STRIDE * n + 1]);
    const float c = wrap_pi(out[(size_t)STRIDE * n + 2]);
    const float cb = __cosf(0.5f * b);
    const float sb = __sinf(0.5f * b);
    const float hpc = 0.5f * (a + c);
    const float hmc = 0.5f * (a - c);
    const float cpc = __cosf(hpc), spc = __sinf(hpc);
    const float cmc = __cosf(hmc), smc = __sinf(hmc);
    float Ur[2][2], Ui[2][2];
    Ur[0][0] =  cpc * cb;  Ui[0][0] = -spc * cb;
    Ur[0][1] = -cmc * sb;  Ui[0][1] =  smc * sb;
    Ur[1][0] =  cmc * sb;  Ui[1][0] =  smc * sb;
    Ur[1][1] =  cpc * cb;  Ui[1][1] =  spc * cb;
    const float4 h4r = *reinterpret_cast<const float4*>(hr + 4 * (size_t)n);
    const float4 h4i = *reinterpret_cast<const float4*>(hi + 4 * (size_t)n);
    float Hr[2][2] = {{h4r.x, h4r.y}, {h4r.z, h4r.w}};
    float Hi[2][2] = {{h4i.x, h4i.y}, {h4i.z, h4i.w}};
    float Tr[2][2], Ti[2][2];
    #pragma unroll
    for (int p = 0; p < 2; ++p) {
        #pragma unroll
        for (int j = 0; j < 2; ++j) {
            float tr = 0.0f, ti = 0.0f;
            #pragma unroll
            for (int t = 0; t < 2; ++t) {
                tr += Hr[p][t] * Ur[j][t] + Hi[p][t] * Ui[j][t];
                ti += Hi[p][t] * Ur[j][t] - Hr[p][t] * Ui[j][t];
            }
            Tr[p][j] = tr; Ti[p][j] = ti;
        }
    }
    float orr[2][2], oii[2][2];
    #pragma unroll
    for (int i = 0; i < 2; ++i) {
        #pragma unroll
        for (int j = 0; j < 2; ++j) {
            float xr = 0.0f, xi = 0.0f;
            #pragma unroll
            for (int p = 0; p < 2; ++p) {
                xr += Ur[i][p] * Tr[p][j] - Ui[i][p] * Ti[p][j];
                xi += Ur[i][p] * Ti[p][j] + Ui[i][p] * Tr[p][j];
            }
            orr[i][j] = xr; oii[i][j] = xi;
        }
    }
    if (WRITE_COMPLEX) {
        float4* outv = reinterpret_cast<float4*>(out + (size_t)STRIDE * n);
        outv[0] = make_float4(orr[0][0], oii[0][0], orr[0][1], oii[0][1]);
        outv[1] = make_float4(orr[1][0], oii[1][0], orr[1][1], oii[1][1]);
    } else {
        *reinterpret_cast<float4*>(out + (size_t)STRIDE * n) =
            make_float4(orr[0][0], orr[0][1], orr[1][0], orr[1][1]);
    }
}

extern "C" void kernel_launch(void* const* d_in, const int* in_sizes, int n_in,
                              void* d_out, int out_size, void* d_ws, size_t ws_size,
                              hipStream_t stream) {
    const float* hr   = (const float*)d_in[0];
    const float* hi   = (const float*)d_in[1];
    const int*   ei   = (const int*)  d_in[2];
    const float* npar = (const float*)d_in[3];
    const float* epar = (const float*)d_in[4];
    const float* Wa  = (const float*)d_in[5];
    const float* ba  = (const float*)d_in[6];
    const float* Wr1 = (const float*)d_in[7];
    const float* br1 = (const float*)d_in[8];
    const float* Wr2 = (const float*)d_in[9];
    const float* br2 = (const float*)d_in[10];
    const float* Wr3 = (const float*)d_in[11];
    const float* br3 = (const float*)d_in[12];
    const float* Wi1 = (const float*)d_in[13];
    const float* bi1 = (const float*)d_in[14];
    const float* Wi2 = (const float*)d_in[15];
    const float* bi2 = (const float*)d_in[16];
    const float* Wi3 = (const float*)d_in[17];
    const float* bi3 = (const float*)d_in[18];

    const int N = in_sizes[0] / 4;   // h_i_real is (N,2,2)
    const int E = in_sizes[2] / 2;   // edge_index is (2,E)

    float* out = (float*)d_out;
    const bool cplx = (out_size >= 8 * N);
    const int stride = cplx ? 8 : 4;
    const int total = stride * N;
    qgnn_zero_kernel<<<(total + 255) / 256, 256, 0, stream>>>(out, total);

    const bool use_mfma = (ws_size >= (size_t)WS_BYTES_NEEDED);
    if (use_mfma) {
        qgnn_prep_kernel<<<56, 256, 0, stream>>>(Wr1, Wr2, Wr3, Wi1, Wi2, Wi3,
                                                 br1, bi1, (unsigned short*)d_ws);
        const int ntiles = (E + 31) / 32;
        int blocks = (ntiles + NW - 1) / NW;
        if (blocks > 4096) blocks = 4096;
        qgnn_edge_mfma_kernel<<<blocks, 256, 0, stream>>>(
            hr, hi, ei, npar, epar, Wa, ba,
            br2, br3, bi2, bi3,
            (const unsigned short*)d_ws, out, E, stride);
    } else if (cplx) {
        qgnn_edge_kernel<8><<<(E + 255) / 256, 256, 0, stream>>>(
            hr, hi, ei, npar, epar, Wa, ba,
            Wr1, br1, Wr2, br2, Wr3, br3,
            Wi1, bi1, Wi2, bi2, Wi3, bi3, out, E);
    } else {
        qgnn_edge_kernel<4><<<(E + 255) / 256, 256, 0, stream>>>(
            hr, hi, ei, npar, epar, Wa, ba,
            Wr1, br1, Wr2, br2, Wr3, br3,
            Wi1, bi1, Wi2, bi2, Wi3, bi3, out, E);
    }

    if (cplx) {
        qgnn_node_kernel<8, true><<<(N + 255) / 256, 256, 0, stream>>>(hr, hi, out, N);
    } else {
        qgnn_node_kernel<4, false><<<(N + 255) / 256, 256, 0, stream>>>(hr, hi, out, N);
    }
}

// Round 23
// 291.588 us; speedup vs baseline: 1.0484x; 1.0173x over previous
//
// Round 23 = re-land r17 (banked best: 292.1 us, absmax 0.03125).
// r22's accuracy-spend (drop L2/L3 W-lo) failed threshold by 2% (0.09375 vs
// 0.091875) -> lever falsified. All levers now tested: occupancy (r15/r17
// neutral), ILP (r18 regression), M=2 amortization (r21 neutral), accuracy
// (r22 fail). Plateau = per-edge VALU/trans stream. This is the final kernel.
#include <hip/hip_runtime.h>

#define PI_F     3.14159265358979323846f
#define TWO_PI_F 6.28318530717958647692f

typedef __attribute__((ext_vector_type(8))) _Float16 half8;
typedef __attribute__((ext_vector_type(4))) float f32x4;

#define LO_SCALE   2048.0f
#define LO_INV     (1.0f / 2048.0f)

__device__ __forceinline__ float fast_rcp(float x) { return __builtin_amdgcn_rcpf(x); }
__device__ __forceinline__ float silu_f(float v) { return v * fast_rcp(1.0f + __expf(-v)); }
__device__ __forceinline__ float tanh_f(float z) {
    float ez = __expf(2.0f * z);
    return 1.0f - 2.0f * fast_rcp(ez + 1.0f);
}

// ---------------- prep: fragment-ordered fp16 hi / scaled-lo weight planes --
// Fragment layout validated r8-r21: per MLP (u16): L1 [0,2048) KT=1 NT=4;
// L2 [2048,6144) KT=2 NT=4; L3 [6144,7168) KT=2 NT=1. MLP i at +7168.
// hi plane [0,14336), scaled-lo plane [14336,28672).
// Frag elem ((kt*NT+nt)*64+lane)*8+j = W[kt*32+8*(lane>>4)+j][nt*16+(lane&15)].
#define WS_U16_TOTAL 28672
#define WS_BYTES_NEEDED (WS_U16_TOTAL * 2)
#define W_HI_U16 14336

__global__ __launch_bounds__(256) void qgnn_prep_kernel(
    const float* __restrict__ Wr1, const float* __restrict__ Wr2, const float* __restrict__ Wr3,
    const float* __restrict__ Wi1, const float* __restrict__ Wi2, const float* __restrict__ Wi3,
    unsigned short* __restrict__ wsu)
{
    int idx = blockIdx.x * 256 + threadIdx.x;
    if (idx >= 14336) return;
    int rel = idx;
    int half = (rel >= 7168);
    if (half) rel -= 7168;
    const float* W; int base, NT, Kr, Nr;
    if (rel < 2048)      { W = half ? Wi1 : Wr1; base = 0;    NT = 4; Kr = 14; Nr = 64; }
    else if (rel < 6144) { W = half ? Wi2 : Wr2; base = 2048; NT = 4; Kr = 64; Nr = 64; }
    else                 { W = half ? Wi3 : Wr3; base = 6144; NT = 1; Kr = 64; Nr = 4;  }
    int f = rel - base;
    int frag = f >> 9, rem = f & 511;
    int l = rem >> 3, j = rem & 7;
    int nt = frag % NT, kt = frag / NT;
    int k = kt * 32 + ((l >> 4) << 3) + j;
    int n = nt * 16 + (l & 15);
    float v = (k < Kr && n < Nr) ? W[k * Nr + n] : 0.0f;
    _Float16 hi = (_Float16)v;                                  // RNE
    _Float16 lo = (_Float16)((v - (float)hi) * LO_SCALE);       // scaled residual
    wsu[idx] = *reinterpret_cast<unsigned short*>(&hi);
    wsu[14336 + idx] = *reinterpret_cast<unsigned short*>(&lo);
}

__global__ __launch_bounds__(256) void qgnn_zero_kernel(float* __restrict__ p, int n) {
    const int i = blockIdx.x * blockDim.x + threadIdx.x;
    if (i < n) p[i] = 0.0f;
}

#define MFMA16(a, b, c) __builtin_amdgcn_mfma_f32_16x16x32_f16((a), (b), (c), 0, 0, 0)
#define NW 4   // waves per block

// One MLP: X(16x32 fp16 hi + scaled lo) -> 64 -> 64 -> 4.
// Biases by value (f32x4); wh: LDS hi plane; wls: global scaled-lo plane.
__device__ __forceinline__ void run_mlp(
    half8 ah, half8 als,
    const _Float16* __restrict__ wh,
    const unsigned short* __restrict__ wls,
    f32x4 b1v, f32x4 b2v, float b3v,
    _Float16* __restrict__ H, float* __restrict__ h3out,
    int lane, int m16, int g)
{
    // ---------- Layer 1: (16x32) @ (32x64), 3 MFMAs ----------
    #pragma unroll 2
    for (int nt = 0; nt < 4; ++nt) {
        const float bv = b1v[nt];
        f32x4 accm = {bv, bv, bv, bv};
        f32x4 accc = {0.f, 0.f, 0.f, 0.f};
        const half8 bh  = *reinterpret_cast<const half8*>(&wh[(nt * 64 + lane) * 8]);
        const half8 bls = *reinterpret_cast<const half8*>(&wls[(nt * 64 + lane) * 8]);
        accm = MFMA16(ah, bh, accm);
        accc = MFMA16(als, bh, accc);     // scaled X-lo x W-hi
        accc = MFMA16(ah, bls, accc);     // X-hi x scaled W-lo
        #pragma unroll
        for (int i = 0; i < 4; ++i) {
            const float hv = silu_f(accm[i] + accc[i] * LO_INV);
            H[(4 * g + i) * 72 + nt * 16 + m16] = (_Float16)hv;   // RNE, single fp16
        }
    }

    // ---------- Layer 2: (16x64) @ (64x64), 4 MFMAs per nt ----------
    {
        const half8 a0 = *reinterpret_cast<const half8*>(&H[m16 * 72 + 8 * g]);
        const half8 a1 = *reinterpret_cast<const half8*>(&H[m16 * 72 + 32 + 8 * g]);
        #pragma unroll 2
        for (int nt = 0; nt < 4; ++nt) {
            const float bv = b2v[nt];
            f32x4 accm = {bv, bv, bv, bv};
            f32x4 accc = {0.f, 0.f, 0.f, 0.f};
            const half8 bh0  = *reinterpret_cast<const half8*>(&wh[2048 + ((0 * 4 + nt) * 64 + lane) * 8]);
            const half8 bls0 = *reinterpret_cast<const half8*>(&wls[2048 + ((0 * 4 + nt) * 64 + lane) * 8]);
            const half8 bh1  = *reinterpret_cast<const half8*>(&wh[2048 + ((1 * 4 + nt) * 64 + lane) * 8]);
            const half8 bls1 = *reinterpret_cast<const half8*>(&wls[2048 + ((1 * 4 + nt) * 64 + lane) * 8]);
            accm = MFMA16(a0, bh0, accm);
            accm = MFMA16(a1, bh1, accm);
            accc = MFMA16(a0, bls0, accc);
            accc = MFMA16(a1, bls1, accc);
            #pragma unroll
            for (int i = 0; i < 4; ++i) {
                const float hv = silu_f(accm[i] + accc[i] * LO_INV);
                H[(4 * g + i) * 72 + nt * 16 + m16] = (_Float16)hv;  // overwrite ok: a0/a1 in regs
            }
        }
    }

    // ---------- Layer 3: (16x64) @ (64x16), 4 valid cols, 4 MFMAs ----------
    {
        const half8 a0 = *reinterpret_cast<const half8*>(&H[m16 * 72 + 8 * g]);
        const half8 a1 = *reinterpret_cast<const half8*>(&H[m16 * 72 + 32 + 8 * g]);
        f32x4 accm = {b3v, b3v, b3v, b3v};
        f32x4 accc = {0.f, 0.f, 0.f, 0.f};
        const half8 bh0  = *reinterpret_cast<const half8*>(&wh[6144 + (0 * 64 + lane) * 8]);
        const half8 bls0 = *reinterpret_cast<const half8*>(&wls[6144 + (0 * 64 + lane) * 8]);
        const half8 bh1  = *reinterpret_cast<const half8*>(&wh[6144 + (1 * 64 + lane) * 8]);
        const half8 bls1 = *reinterpret_cast<const half8*>(&wls[6144 + (1 * 64 + lane) * 8]);
        accm = MFMA16(a0, bh0, accm);
        accm = MFMA16(a1, bh1, accm);
        accc = MFMA16(a0, bls0, accc);
        accc = MFMA16(a1, bls1, accc);
        if (m16 < 4) {
            #pragma unroll
            for (int i = 0; i < 4; ++i)
                h3out[(4 * g + i) * 8 + m16] = accm[i] + accc[i] * LO_INV;
        }
    }
}

__global__ __launch_bounds__(256, 4) void qgnn_edge_mfma_kernel(
    const float* __restrict__ hr, const float* __restrict__ hi_,
    const int* __restrict__ ei,
    const float* __restrict__ npar, const float* __restrict__ epar,
    const float* __restrict__ Wa, const float* __restrict__ ba,
    const float* __restrict__ br1, const float* __restrict__ br2, const float* __restrict__ br3,
    const float* __restrict__ bi1, const float* __restrict__ bi2, const float* __restrict__ bi3,
    const unsigned short* __restrict__ wsu,
    float* __restrict__ aggout, int E, int stride)
{
    __shared__ __align__(16) _Float16 sW[W_HI_U16];            // 28672 B (hi plane)
    __shared__ __align__(16) _Float16 sH[NW][16 * 72];         // 4x2304 B
    __shared__ __align__(16) float sH3[NW][16 * 8];            // 4x512 B
    // total 39936 B -> LDS allows 4 blocks/CU

    // ---- stage hi-plane weights once (the only barrier in this kernel) ----
    {
        unsigned short* sWu = reinterpret_cast<unsigned short*>(sW);
        for (int o = threadIdx.x * 8; o < W_HI_U16; o += 256 * 8)
            *reinterpret_cast<uint4*>(sWu + o) = *reinterpret_cast<const uint4*>(wsu + o);
    }
    __syncthreads();

    const int tid = threadIdx.x, w = tid >> 6, lane = tid & 63;
    const int m16 = lane & 15, g = lane >> 4;
    _Float16* H = sH[w];
    float* H3 = sH3[w];

    // ---- per-lane constants: vector-typed, by-value use only (registers) ----
    f32x4 br1v, br2v, bi1v, bi2v;
    #pragma unroll
    for (int q = 0; q < 4; ++q) {
        br1v[q] = br1[q * 16 + m16];
        br2v[q] = br2[q * 16 + m16];
        bi1v[q] = bi1[q * 16 + m16];
        bi2v[q] = bi2[q * 16 + m16];
    }
    const float br3v = (m16 < 4) ? br3[m16] : 0.0f;
    const float bi3v = (m16 < 4) ? bi3[m16] : 0.0f;
    float wav[24], bav[3];
    #pragma unroll
    for (int q = 0; q < 24; ++q) wav[q] = Wa[q];
    #pragma unroll
    for (int q = 0; q < 3; ++q) bav[q] = ba[q];

    const int ntiles = (E + 15) >> 4;
    for (int tile = blockIdx.x * NW + w; tile < ntiles; tile += gridDim.x * NW) {
        const int em = tile * 16 + m16;
        const bool valid = (em < E);

        // ---- gather X straight into registers (no LDS, no barrier) ----
        float f0[8], f1[8];
        #pragma unroll
        for (int j = 0; j < 8; ++j) { f0[j] = 0.0f; f1[j] = 0.0f; }
        if (valid && g < 2) {
            const int s = ei[em], r = ei[E + em];
            if (g == 0) {
                const float4 a = *reinterpret_cast<const float4*>(hr  + 4 * (size_t)s);
                const float4 b = *reinterpret_cast<const float4*>(hr  + 4 * (size_t)r);
                const float4 c = *reinterpret_cast<const float4*>(hi_ + 4 * (size_t)s);
                const float4 d = *reinterpret_cast<const float4*>(hi_ + 4 * (size_t)r);
                f0[0] = a.x; f0[1] = a.y; f0[2] = a.z; f0[3] = a.w;
                f0[4] = b.x; f0[5] = b.y; f0[6] = b.z; f0[7] = b.w;
                f1[0] = c.x; f1[1] = c.y; f1[2] = c.z; f1[3] = c.w;
                f1[4] = d.x; f1[5] = d.y; f1[6] = d.z; f1[7] = d.w;
            } else {
                const float2 n0 = *reinterpret_cast<const float2*>(npar + 2 * (size_t)s);
                const float2 n1 = *reinterpret_cast<const float2*>(npar + 2 * (size_t)r);
                const float e0 = epar[ei[2 * em + 0]];
                const float e1 = epar[ei[2 * em + 1]];
                f0[0] = n0.x; f0[1] = n0.y; f0[2] = n1.x; f0[3] = n1.y;
                f0[4] = e0;   f0[5] = e1;
                #pragma unroll
                for (int j = 0; j < 6; ++j) f1[j] = f0[j];
            }
        }
        half8 xh0, xls0, xh1, xls1;
        #pragma unroll
        for (int j = 0; j < 8; ++j) {
            const _Float16 h0 = (_Float16)f0[j];
            xh0[j] = h0;
            xls0[j] = (_Float16)((f0[j] - (float)h0) * LO_SCALE);
            const _Float16 h1 = (_Float16)f1[j];
            xh1[j] = h1;
            xls1[j] = (_Float16)((f1[j] - (float)h1) * LO_SCALE);
        }

        run_mlp(xh0, xls0, sW, wsu + W_HI_U16,
                br1v, br2v, br3v, H, H3 + 0, lane, m16, g);
        run_mlp(xh1, xls1, sW + 7168, wsu + W_HI_U16 + 7168,
                bi1v, bi2v, bi3v, H, H3 + 4, lane, m16, g);

        // ---- epilogue: 16 lanes, one edge each (wave-internal LDS, no barrier)
        if (lane < 16) {
            const int e2 = tile * 16 + lane;
            if (e2 < E) {
                const float4 Ai4 = *reinterpret_cast<const float4*>(&H3[lane * 8 + 4]);
                const float4 Ar4 = *reinterpret_cast<const float4*>(&H3[lane * 8 + 0]);
                const float Ai[4] = {Ai4.x, Ai4.y, Ai4.z, Ai4.w};
                const float Ar[4] = {Ar4.x, Ar4.y, Ar4.z, Ar4.w};
                const int r = ei[E + e2];
                #pragma unroll
                for (int t = 0; t < 3; ++t) {
                    float z = bav[t];
                    #pragma unroll
                    for (int j = 0; j < 4; ++j) z += Ai[j] * wav[j * 3 + t];
                    #pragma unroll
                    for (int j = 0; j < 4; ++j) z += Ar[j] * wav[(4 + j) * 3 + t];
                    atomicAdd(aggout + (size_t)stride * (size_t)r + t, tanh_f(z) * PI_F);
                }
            }
        }
    }
}

// ---------------- round-6 scalar fallback (ws too small) ----------------
__device__ __forceinline__ void mlp14_64_64_4(
    const float x[14],
    const float* __restrict__ W1, const float* __restrict__ b1,
    const float* __restrict__ W2, const float* __restrict__ b2,
    const float* __restrict__ W3, const float* __restrict__ b3,
    float A[4])
{
    float h1[64];
    #pragma unroll
    for (int j = 0; j < 64; ++j) h1[j] = b1[j];
    #pragma unroll
    for (int k = 0; k < 14; ++k) {
        const float xk = x[k];
        #pragma unroll
        for (int j = 0; j < 64; ++j) h1[j] += xk * W1[k * 64 + j];
    }
    #pragma unroll
    for (int j = 0; j < 64; ++j) h1[j] = silu_f(h1[j]);
    float h2[64];
    #pragma unroll
    for (int j = 0; j < 64; ++j) h2[j] = b2[j];
    #pragma unroll
    for (int k = 0; k < 64; ++k) {
        const float hk = h1[k];
        #pragma unroll
        for (int j = 0; j < 64; ++j) h2[j] += hk * W2[k * 64 + j];
    }
    #pragma unroll
    for (int j = 0; j < 64; ++j) h2[j] = silu_f(h2[j]);
    float a0 = b3[0], a1 = b3[1], a2 = b3[2], a3 = b3[3];
    #pragma unroll
    for (int k = 0; k < 64; ++k) {
        const float hk = h2[k];
        a0 += hk * W3[k * 4 + 0];
        a1 += hk * W3[k * 4 + 1];
        a2 += hk * W3[k * 4 + 2];
        a3 += hk * W3[k * 4 + 3];
    }
    A[0] = a0; A[1] = a1; A[2] = a2; A[3] = a3;
}

template<int STRIDE>
__global__ __launch_bounds__(256) void qgnn_edge_kernel(
    const float* __restrict__ hr, const float* __restrict__ hi,
    const int* __restrict__ ei,
    const float* __restrict__ npar, const float* __restrict__ epar,
    const float* __restrict__ Wa, const float* __restrict__ ba,
    const float* __restrict__ Wr1, const float* __restrict__ br1,
    const float* __restrict__ Wr2, const float* __restrict__ br2,
    const float* __restrict__ Wr3, const float* __restrict__ br3,
    const float* __restrict__ Wi1, const float* __restrict__ bi1,
    const float* __restrict__ Wi2, const float* __restrict__ bi2,
    const float* __restrict__ Wi3, const float* __restrict__ bi3,
    float* __restrict__ aggout, int E)
{
    const int e = blockIdx.x * blockDim.x + threadIdx.x;
    if (e >= E) return;
    const int s = ei[e];
    const int r = ei[E + e];
    const float ep0 = epar[ei[2 * e + 0]];
    const float ep1 = epar[ei[2 * e + 1]];
    const float4 hrs = *reinterpret_cast<const float4*>(hr + 4 * (size_t)s);
    const float4 hrr = *reinterpret_cast<const float4*>(hr + 4 * (size_t)r);
    const float2 nps = *reinterpret_cast<const float2*>(npar + 2 * (size_t)s);
    const float2 npr = *reinterpret_cast<const float2*>(npar + 2 * (size_t)r);
    float x[14];
    x[0] = hrs.x; x[1] = hrs.y; x[2] = hrs.z; x[3] = hrs.w;
    x[4] = hrr.x; x[5] = hrr.y; x[6] = hrr.z; x[7] = hrr.w;
    x[8] = nps.x; x[9] = nps.y; x[10] = npr.x; x[11] = npr.y;
    x[12] = ep0;  x[13] = ep1;
    float Ar[4];
    mlp14_64_64_4(x, Wr1, br1, Wr2, br2, Wr3, br3, Ar);
    const float4 his = *reinterpret_cast<const float4*>(hi + 4 * (size_t)s);
    const float4 hir = *reinterpret_cast<const float4*>(hi + 4 * (size_t)r);
    x[0] = his.x; x[1] = his.y; x[2] = his.z; x[3] = his.w;
    x[4] = hir.x; x[5] = hir.y; x[6] = hir.z; x[7] = hir.w;
    float Ai[4];
    mlp14_64_64_4(x, Wi1, bi1, Wi2, bi2, Wi3, bi3, Ai);
    #pragma unroll
    for (int t = 0; t < 3; ++t) {
        float z = ba[t];
        #pragma unroll
        for (int j = 0; j < 4; ++j) z += Ai[j] * Wa[j * 3 + t];
        #pragma unroll
        for (int j = 0; j < 4; ++j) z += Ar[j] * Wa[(4 + j) * 3 + t];
        atomicAdd(aggout + (size_t)STRIDE * (size_t)r + t, tanh_f(z) * PI_F);
    }
}

// ---------------- node kernel ----------------
__device__ __forceinline__ float wrap_pi(float v) {
    float rm = fmodf(v + PI_F, TWO_PI_F);
    if (rm < 0.0f) rm += TWO_PI_F;
    return rm - PI_F;
}

template<int STRIDE, bool WRITE_COMPLEX>
__global__ __launch_bounds__(256) void qgnn_node_kernel(
    const float* __restrict__ hr,
    const float* __restrict__ hi,
    float* __restrict__ out, int N)
{
    const int n = blockIdx.x * blockDim.x + threadIdx.x;
    if (n >= N) return;
    const float a = wrap_pi(out[(size_t)STRIDE * n + 0]);
    const float b = wrap_pi(out[(size_t)STRIDE * n + 1]);
    const float c = wrap_pi(out[(size_t)STRIDE * n + 2]);
    const float cb = __cosf(0.5f * b);
    const float sb = __sinf(0.5f * b);
    const float hpc = 0.5f * (a + c);
    const float hmc = 0.5f * (a - c);
    const float cpc = __cosf(hpc), spc = __sinf(hpc);
    const float cmc = __cosf(hmc), smc = __sinf(hmc);
    float Ur[2][2], Ui[2][2];
    Ur[0][0] =  cpc * cb;  Ui[0][0] = -spc * cb;
    Ur[0][1] = -cmc * sb;  Ui[0][1] =  smc * sb;
    Ur[1][0] =  cmc * sb;  Ui[1][0] =  smc * sb;
    Ur[1][1] =  cpc * cb;  Ui[1][1] =  spc * cb;
    const float4 h4r = *reinterpret_cast<const float4*>(hr + 4 * (size_t)n);
    const float4 h4i = *reinterpret_cast<const float4*>(hi + 4 * (size_t)n);
    float Hr[2][2] = {{h4r.x, h4r.y}, {h4r.z, h4r.w}};
    float Hi[2][2] = {{h4i.x, h4i.y}, {h4i.z, h4i.w}};
    float Tr[2][2], Ti[2][2];
    #pragma unroll
    for (int p = 0; p < 2; ++p) {
        #pragma unroll
        for (int j = 0; j < 2; ++j) {
            float tr = 0.0f, ti = 0.0f;
            #pragma unroll
            for (int t = 0; t < 2; ++t) {
                tr += Hr[p][t] * Ur[j][t] + Hi[p][t] * Ui[j][t];
                ti += Hi[p][t] * Ur[j][t] - Hr[p][t] * Ui[j][t];
            }
            Tr[p][j] = tr; Ti[p][j] = ti;
        }
    }
    float orr[2][2], oii[2][2];
    #pragma unroll
    for (int i = 0; i < 2; ++i) {
        #pragma unroll
        for (int j = 0; j < 2; ++j) {
            float xr = 0.0f, xi = 0.0f;
            #pragma unroll
            for (int p = 0; p < 2; ++p) {
                xr += Ur[i][p] * Tr[p][j] - Ui[i][p] * Ti[p][j];
                xi += Ur[i][p] * Ti[p][j] + Ui[i][p] * Tr[p][j];
            }
            orr[i][j] = xr; oii[i][j] = xi;
        }
    }
    if (WRITE_COMPLEX) {
        float4* outv = reinterpret_cast<float4*>(out + (size_t)STRIDE * n);
        outv[0] = make_float4(orr[0][0], oii[0][0], orr[0][1], oii[0][1]);
        outv[1] = make_float4(orr[1][0], oii[1][0], orr[1][1], oii[1][1]);
    } else {
        *reinterpret_cast<float4*>(out + (size_t)STRIDE * n) =
            make_float4(orr[0][0], orr[0][1], orr[1][0], orr[1][1]);
    }
}

extern "C" void kernel_launch(void* const* d_in, const int* in_sizes, int n_in,
                              void* d_out, int out_size, void* d_ws, size_t ws_size,
                              hipStream_t stream) {
    const float* hr   = (const float*)d_in[0];
    const float* hi   = (const float*)d_in[1];
    const int*   ei   = (const int*)  d_in[2];
    const float* npar = (const float*)d_in[3];
    const float* epar = (const float*)d_in[4];
    const float* Wa  = (const float*)d_in[5];
    const float* ba  = (const float*)d_in[6];
    const float* Wr1 = (const float*)d_in[7];
    const float* br1 = (const float*)d_in[8];
    const float* Wr2 = (const float*)d_in[9];
    const float* br2 = (const float*)d_in[10];
    const float* Wr3 = (const float*)d_in[11];
    const float* br3 = (const float*)d_in[12];
    const float* Wi1 = (const float*)d_in[13];
    const float* bi1 = (const float*)d_in[14];
    const float* Wi2 = (const float*)d_in[15];
    const float* bi2 = (const float*)d_in[16];
    const float* Wi3 = (const float*)d_in[17];
    const float* bi3 = (const float*)d_in[18];

    const int N = in_sizes[0] / 4;   // h_i_real is (N,2,2)
    const int E = in_sizes[2] / 2;   // edge_index is (2,E)

    float* out = (float*)d_out;
    const bool cplx = (out_size >= 8 * N);
    const int stride = cplx ? 8 : 4;
    const int total = stride * N;
    qgnn_zero_kernel<<<(total + 255) / 256, 256, 0, stream>>>(out, total);

    const bool use_mfma = (ws_size >= (size_t)WS_BYTES_NEEDED);
    if (use_mfma) {
        qgnn_prep_kernel<<<56, 256, 0, stream>>>(Wr1, Wr2, Wr3, Wi1, Wi2, Wi3,
                                                 (unsigned short*)d_ws);
        const int ntiles = (E + 15) / 16;
        int blocks = (ntiles + NW - 1) / NW;
        if (blocks > 4096) blocks = 4096;
        qgnn_edge_mfma_kernel<<<blocks, 256, 0, stream>>>(
            hr, hi, ei, npar, epar, Wa, ba,
            br1, br2, br3, bi1, bi2, bi3,
            (const unsigned short*)d_ws, out, E, stride);
    } else if (cplx) {
        qgnn_edge_kernel<8><<<(E + 255) / 256, 256, 0, stream>>>(
            hr, hi, ei, npar, epar, Wa, ba,
            Wr1, br1, Wr2, br2, Wr3, br3,
            Wi1, bi1, Wi2, bi2, Wi3, bi3, out, E);
    } else {
        qgnn_edge_kernel<4><<<(E + 255) / 256, 256, 0, stream>>>(
            hr, hi, ei, npar, epar, Wa, ba,
            Wr1, br1, Wr2, br2, Wr3, br3,
            Wi1, bi1, Wi2, bi2, Wi3, bi3, out, E);
    }

    if (cplx) {
        qgnn_node_kernel<8, true><<<(N + 255) / 256, 256, 0, stream>>>(hr, hi, out, N);
    } else {
        qgnn_node_kernel<4, false><<<(N + 255) / 256, 256, 0, stream>>>(hr, hi, out, N);
    }
}